// Round 4
// baseline (166.631 us; speedup 1.0000x reference)
//
#include <hip/hip_runtime.h>
#include <cstdint>

// MXFP4 fake-quant linear: out = qdq(A) @ qdq(W)^T + bias
// Stage 1: quantize fp32 -> packed e2m1 + e8m0 scales (TRANSPOSED scale
//          layout AscT[kblk][m], WscT[kblk][n]; verified round 3).
// Stage 2: fp4 GEMM, 256x128 tile, 512 threads (8 waves 4Mx2N), NBUF=3
//          circular LDS, 2 sub-phases per K-tile (phase-split schedule),
//          counted vmcnt(3) (no drain in main loop), setprio around MFMA
//          clusters, XCD-aware remap, 2 WGs/CU.

#define BM 256
#define BN 128
#define BK 128      // K elements per tile = one mfma_scale k-step
#define NBUF 3

typedef float floatx4 __attribute__((ext_vector_type(4)));
typedef int intx8 __attribute__((ext_vector_type(8)));

#define GLOBAL_AS __attribute__((address_space(1)))
#define LDS_AS __attribute__((address_space(3)))

// ---------------- quantize fp32 -> packed fp4 + e8m0 scales ----------------

__device__ __forceinline__ int enc1(float x, float inv) {
    float q = x * inv;                         // inv = 2^-(e-2), exact
    q = fminf(fmaxf(q, -6.0f), 6.0f);
    int s = (int)(__float_as_uint(q) >> 31) << 3;
    float aq = fabsf(q);
    float ilsb = aq < 2.0f ? 2.0f : (aq < 4.0f ? 1.0f : 0.5f);
    float lsb  = aq < 2.0f ? 0.5f : (aq < 4.0f ? 1.0f : 2.0f);
    float ar = rintf(aq * ilsb) * lsb;         // RNE onto e2m1 grid
    int c;
    if (ar < 2.0f)      c = (int)(ar * 2.0f);  // 0,.5,1,1.5 -> 0..3
    else if (ar < 4.0f) c = 2 + (int)ar;       // 2,3 -> 4,5
    else                c = 4 + (int)(ar * 0.5f); // 4,6 -> 6,7
    return c | s;
}

__global__ void quant_mxfp4_v4(const float* __restrict__ A, uint8_t* __restrict__ Aq,
                               uint8_t* __restrict__ AscT,
                               const float* __restrict__ W, uint8_t* __restrict__ Wq,
                               uint8_t* __restrict__ WscT,
                               long na4, long ntot4, int s4, long Mr, long Nr) {
    long t = (long)blockIdx.x * 256 + threadIdx.x;
    if (t >= ntot4) return;
    const float* src; uint8_t* dq; uint8_t* ds; long idx; long rows;
    if (t < na4) { src = A; dq = Aq; ds = AscT; idx = t; rows = Mr; }
    else         { src = W; dq = Wq; ds = WscT; idx = t - na4; rows = Nr; }

    float4 f = ((const float4*)src)[idx];
    float amax = fmaxf(fmaxf(fabsf(f.x), fabsf(f.y)),
                       fmaxf(fabsf(f.z), fabsf(f.w)));
    amax = fmaxf(amax, __shfl_xor(amax, 1));
    amax = fmaxf(amax, __shfl_xor(amax, 2));
    amax = fmaxf(amax, __shfl_xor(amax, 4));

    int ebits = (int)((__float_as_uint(amax) >> 23) & 0xff);
    int sb;
    float inv;
    if (amax > 0.0f) {
        sb = ebits - 2; if (sb < 0) sb = 0;
        inv = __uint_as_float((unsigned)((256 - ebits) & 255) << 23);
    } else {
        sb = 127;              // scale 1.0, all-zero block
        inv = 0.0f;
    }

    int c0 = enc1(f.x, inv), c1 = enc1(f.y, inv);
    int c2 = enc1(f.z, inv), c3 = enc1(f.w, inv);
    ((unsigned short*)dq)[idx] =
        (unsigned short)(c0 | (c1 << 4) | (c2 << 8) | (c3 << 12));
    if ((idx & 7) == 0) {
        long m  = idx >> s4;                       // row
        int  kb = (int)((idx & ((1L << s4) - 1)) >> 3);  // k-block
        ds[(size_t)kb * rows + m] = (uint8_t)sb;   // transposed: [kb][row]
    }
}

// ---------- fp4 GEMM: C[M,N] = (Aq,AscT) x (Wq,WscT)^T + bias ----------
// 512 threads = 8 waves 4(M) x 2(N); per-wave output 64x64 (acc[4][4]).
// A-frag (16x16x128): row = lane&15, k-block = lane>>4 (16B = 32 elems).
// C/D: col(lane&15)=n, row((lane>>4)*4+reg)=m. Verified rounds 1-3.
//
// Per K-tile: 2 sub-phases, each {ds_read frags, issue stage-chunk of
// tile t+2, barrier, lgkmcnt(0), setprio, 8 MFMA, setprio, barrier}.
// End-of-tile: vmcnt(3) = keep t+2's loads in flight, t+1 guaranteed
// landed (per-wave DMA/tile <= 4; FIFO). NBUF=3 ring.
//
// XCD remap (grid 512, id%8 = XCD): per-XCD set = 4 A-panels (1 MB) +
// whole W (2.1 MB) < 4 MB L2.

__global__ __launch_bounds__(512, 4) void gemm_fp4_v5(
        const uint8_t* __restrict__ Aq, const uint8_t* __restrict__ AscT,
        const uint8_t* __restrict__ Wq, const uint8_t* __restrict__ WscT,
        const float* __restrict__ bias, float* __restrict__ C,
        int M, int N, int K) {
    __shared__ __align__(16) uint8_t sA[NBUF][BM * 64];   // 3 x 16 KB
    __shared__ __align__(16) uint8_t sB[NBUF][BN * 64];   // 3 x 8 KB
    __shared__ __align__(16) uint8_t sSA[NBUF][4 * BM];   // 3 x 1 KB [kb][m]
    __shared__ __align__(16) uint8_t sSB[NBUF][4 * BN];   // 3 x 512 B [kb][n]

    const int tid = threadIdx.x;
    const int lane = tid & 63;
    const int w = tid >> 6;
    const int wr = w >> 1;           // 0..3 (M)
    const int wc = w & 1;            // 0..1 (N)
    const int row16 = lane & 15;
    const int quad = lane >> 4;      // k-block index within tile

    // XCD-aware bijective remap: g=XCD, by = g + 8*(h&3), bx = h>>2
    const int id = blockIdx.x;
    const int g = id & 7, h = id >> 3;
    const int by = g + 8 * (h & 3);  // 0..31
    const int bx = h >> 2;           // 0..15
    const int m0 = by * BM;
    const int n0 = bx * BN;
    const int KB2 = K >> 1;
    const int NT = K / BK;           // 16

    const int rA = wr * 64 + row16;  // A row within tile
    const int rB = wc * 64 + row16;  // B row within tile

    floatx4 acc[4][4];
#pragma unroll
    for (int i = 0; i < 4; i++)
#pragma unroll
        for (int j = 0; j < 4; j++) acc[i][j] = (floatx4){0.f, 0.f, 0.f, 0.f};

    // ---- staging: split so each sub-phase issues ~half the tile's DMA ----
    // per-wave DMA/tile: waves0-1: 2A+1B+1Bs=4, waves2-3: 3, waves4-7: 4.
    auto stageA = [&](int tt) {          // 2 x 16B insts, all threads
        const int bb = tt % NBUF;
        const int kb = tt * 64;
#pragma unroll
        for (int it = 0; it < 2; ++it) {
            int idx = it * 512 + tid;    // 0..1023 16B chunks
            int row = idx >> 2, c = idx & 3;
            const uint8_t* src = Aq + (size_t)(m0 + row) * KB2 + kb + c * 16;
            __builtin_amdgcn_global_load_lds((GLOBAL_AS void*)src,
                (LDS_AS void*)(&sA[bb][idx * 16]), 16, 0, 0);
        }
    };
    auto stageB = [&](int tt) {          // B data + both scale planes
        const int bb = tt % NBUF;
        const int kb = tt * 64;
        {
            int row = tid >> 2, c = tid & 3;   // 512 chunks
            const uint8_t* src = Wq + (size_t)(n0 + row) * KB2 + kb + c * 16;
            __builtin_amdgcn_global_load_lds((GLOBAL_AS void*)src,
                (LDS_AS void*)(&sB[bb][tid * 16]), 16, 0, 0);
        }
        if (tid >= 256) {                 // A scales: 256 thr x 4B = 1 KB
            int local = tid - 256;
            int kbi = local >> 6, moff = (local & 63) * 4;
            const uint8_t* src = AscT + (size_t)(4 * tt + kbi) * M + m0 + moff;
            __builtin_amdgcn_global_load_lds((GLOBAL_AS void*)src,
                (LDS_AS void*)(&sSA[bb][local * 4]), 4, 0, 0);
        } else if (tid < 128) {           // W scales: 128 thr x 4B = 512 B
            int kbi = tid >> 5, noff = (tid & 31) * 4;
            const uint8_t* src = WscT + (size_t)(4 * tt + kbi) * N + n0 + noff;
            __builtin_amdgcn_global_load_lds((GLOBAL_AS void*)src,
                (LDS_AS void*)(&sSB[bb][tid * 4]), 4, 0, 0);
        }
    };

    // ---- prologue: stage tiles 0,1; ensure tile 0 landed (vmcnt(3):
    // conservative for 4-inst waves, exact for 3-inst waves) ----
    stageA(0); stageB(0);
    if (NT > 1) { stageA(1); stageB(1); }
    if (NT > 1) asm volatile("s_waitcnt vmcnt(3)" ::: "memory");
    else        asm volatile("s_waitcnt vmcnt(0)" ::: "memory");
    __builtin_amdgcn_sched_barrier(0);
    __builtin_amdgcn_s_barrier();

    for (int t = 0; t < NT; ++t) {
        const int p = t % NBUF;
        const uint8_t* pa = sA[p];
        const uint8_t* pb = sB[p];

        // ================ sub-phase 0: mi 0,1 x ni 0..3 ================
        int4 bfr[4]; int swb[4];
        int4 afr[2]; int sab[2];
#pragma unroll
        for (int ni = 0; ni < 4; ++ni) {
            int r = rB + ni * 16;
            bfr[ni] = *(const int4*)(pb + r * 64 + quad * 16);
            swb[ni] = (int)sSB[p][quad * BN + wc * 64 + ni * 16 + row16];
        }
#pragma unroll
        for (int mi = 0; mi < 2; ++mi) {
            int r = rA + mi * 16;
            afr[mi] = *(const int4*)(pa + r * 64 + quad * 16);
            sab[mi] = (int)sSA[p][quad * BM + wr * 64 + mi * 16 + row16];
        }
        if (t + 2 < NT) stageA(t + 2);    // buf (t+2)%3 freed after tile t-1

        __builtin_amdgcn_s_barrier();
        asm volatile("s_waitcnt lgkmcnt(0)" ::: "memory");
        __builtin_amdgcn_sched_barrier(0);

        __builtin_amdgcn_s_setprio(1);
#pragma unroll
        for (int mi = 0; mi < 2; ++mi) {
            intx8 a8 = {afr[mi].x, afr[mi].y, afr[mi].z, afr[mi].w, 0, 0, 0, 0};
#pragma unroll
            for (int ni = 0; ni < 4; ++ni) {
                intx8 b8 = {bfr[ni].x, bfr[ni].y, bfr[ni].z, bfr[ni].w, 0, 0, 0, 0};
                acc[mi][ni] = __builtin_amdgcn_mfma_scale_f32_16x16x128_f8f6f4(
                    a8, b8, acc[mi][ni], 4, 4, 0, sab[mi], 0, swb[ni]);
            }
        }
        __builtin_amdgcn_s_setprio(0);
        __builtin_amdgcn_s_barrier();

        // ================ sub-phase 1: mi 2,3 x ni 0..3 ================
#pragma unroll
        for (int mi = 0; mi < 2; ++mi) {
            int r = rA + (mi + 2) * 16;
            afr[mi] = *(const int4*)(pa + r * 64 + quad * 16);
            sab[mi] = (int)sSA[p][quad * BM + wr * 64 + (mi + 2) * 16 + row16];
        }
        if (t + 2 < NT) stageB(t + 2);

        __builtin_amdgcn_s_barrier();
        asm volatile("s_waitcnt lgkmcnt(0)" ::: "memory");
        __builtin_amdgcn_sched_barrier(0);

        __builtin_amdgcn_s_setprio(1);
#pragma unroll
        for (int mi = 0; mi < 2; ++mi) {
            intx8 a8 = {afr[mi].x, afr[mi].y, afr[mi].z, afr[mi].w, 0, 0, 0, 0};
#pragma unroll
            for (int ni = 0; ni < 4; ++ni) {
                intx8 b8 = {bfr[ni].x, bfr[ni].y, bfr[ni].z, bfr[ni].w, 0, 0, 0, 0};
                acc[mi + 2][ni] = __builtin_amdgcn_mfma_scale_f32_16x16x128_f8f6f4(
                    a8, b8, acc[mi + 2][ni], 4, 4, 0, sab[mi], 0, swb[ni]);
            }
        }
        __builtin_amdgcn_s_setprio(0);

        // counted end-of-tile wait: t+1 fully landed, t+2 stays in flight
        if (t < NT - 1) {
            if (t + 2 < NT) asm volatile("s_waitcnt vmcnt(3)" ::: "memory");
            else            asm volatile("s_waitcnt vmcnt(0)" ::: "memory");
            __builtin_amdgcn_sched_barrier(0);
        }
        __builtin_amdgcn_s_barrier();
    }

    // ---- epilogue: C/D col(lane&15)=n, row(quad*4+reg)=m ----
#pragma unroll
    for (int ni = 0; ni < 4; ++ni) {
        int n = n0 + wc * 64 + ni * 16 + row16;
        float bv = bias[n];
#pragma unroll
        for (int mi = 0; mi < 4; ++mi) {
            int mbase = m0 + wr * 64 + mi * 16 + quad * 4;
#pragma unroll
            for (int r = 0; r < 4; ++r) {
                C[(size_t)(mbase + r) * N + n] = acc[mi][ni][r] + bv;
            }
        }
    }
}

// ---------------- launch ----------------

extern "C" void kernel_launch(void* const* d_in, const int* in_sizes, int n_in,
                              void* d_out, int out_size, void* d_ws, size_t ws_size,
                              hipStream_t stream) {
    const float* inp  = (const float*)d_in[0];
    const float* wgt  = (const float*)d_in[1];
    const float* bias = (const float*)d_in[2];
    float* out = (float*)d_out;

    const int N = in_sizes[2];                 // 2048
    const int K = in_sizes[1] / N;             // 2048
    const long M = (long)in_sizes[0] / K;      // 8192

    uint8_t* Aq4  = (uint8_t*)d_ws;            // M*K/2
    uint8_t* Wq4  = Aq4 + (size_t)M * K / 2;   // N*K/2
    uint8_t* AscT = Wq4 + (size_t)N * K / 2;   // M*K/32 (layout [K/32][M])
    uint8_t* WscT = AscT + (size_t)M * K / 32; // N*K/32 (layout [K/32][N])

    int s4 = 0;
    while ((1 << s4) < (K >> 2)) ++s4;         // log2(K/4) = 9

    long na4   = (long)M * K / 4;
    long ntot4 = na4 + (long)N * K / 4;
    quant_mxfp4_v4<<<dim3((ntot4 + 255) / 256), dim3(256), 0, stream>>>(
        inp, Aq4, AscT, wgt, Wq4, WscT, na4, ntot4, s4, M, (long)N);

    dim3 grid((N / BN) * (int)(M / BM));       // 16*32 = 512 WGs = 2/CU
    gemm_fp4_v5<<<grid, dim3(512), 0, stream>>>(
        Aq4, AscT, Wq4, WscT, bias, out, (int)M, N, K);
}

// Round 5
// 153.051 us; speedup vs baseline: 1.0887x; 1.0887x over previous
//
#include <hip/hip_runtime.h>
#include <cstdint>

// MXFP4 fake-quant linear: out = qdq(A) @ qdq(W)^T + bias
// Stage 1: quantize fp32 -> packed e2m1 + e8m0 scales (TRANSPOSED scale
//          layout AscT[kblk][m], WscT[kblk][n]; verified rounds 3-4).
// Stage 2: fp4 GEMM on the r3 skeleton (128x128 tile, 4 waves 2x2, NBUF=2,
//          2 barriers/tile, 4 WGs/CU, XCD remap) with:
//          - 32x32x64 scaled MFMA (2x FLOP/inst vs 16x16x128)
//          - scales loaded global->reg (no LDS round trip)
//          - chunk-XOR swizzle c^((row>>1)&3) for balanced b128 reads

#define BM 128
#define BN 128
#define BK 128      // K elements per tile = 2 k-steps of the 32x32x64 MFMA

typedef float floatx16 __attribute__((ext_vector_type(16)));
typedef int intx8 __attribute__((ext_vector_type(8)));

#define GLOBAL_AS __attribute__((address_space(1)))
#define LDS_AS __attribute__((address_space(3)))

// ---------------- quantize fp32 -> packed fp4 + e8m0 scales ----------------

__device__ __forceinline__ int enc1(float x, float inv) {
    float q = x * inv;                         // inv = 2^-(e-2), exact
    q = fminf(fmaxf(q, -6.0f), 6.0f);
    int s = (int)(__float_as_uint(q) >> 31) << 3;
    float aq = fabsf(q);
    float ilsb = aq < 2.0f ? 2.0f : (aq < 4.0f ? 1.0f : 0.5f);
    float lsb  = aq < 2.0f ? 0.5f : (aq < 4.0f ? 1.0f : 2.0f);
    float ar = rintf(aq * ilsb) * lsb;         // RNE onto e2m1 grid
    int c;
    if (ar < 2.0f)      c = (int)(ar * 2.0f);  // 0,.5,1,1.5 -> 0..3
    else if (ar < 4.0f) c = 2 + (int)ar;       // 2,3 -> 4,5
    else                c = 4 + (int)(ar * 0.5f); // 4,6 -> 6,7
    return c | s;
}

__global__ void quant_mxfp4_v4(const float* __restrict__ A, uint8_t* __restrict__ Aq,
                               uint8_t* __restrict__ AscT,
                               const float* __restrict__ W, uint8_t* __restrict__ Wq,
                               uint8_t* __restrict__ WscT,
                               long na4, long ntot4, int s4, long Mr, long Nr) {
    long t = (long)blockIdx.x * 256 + threadIdx.x;
    if (t >= ntot4) return;
    const float* src; uint8_t* dq; uint8_t* ds; long idx; long rows;
    if (t < na4) { src = A; dq = Aq; ds = AscT; idx = t; rows = Mr; }
    else         { src = W; dq = Wq; ds = WscT; idx = t - na4; rows = Nr; }

    float4 f = ((const float4*)src)[idx];
    float amax = fmaxf(fmaxf(fabsf(f.x), fabsf(f.y)),
                       fmaxf(fabsf(f.z), fabsf(f.w)));
    amax = fmaxf(amax, __shfl_xor(amax, 1));
    amax = fmaxf(amax, __shfl_xor(amax, 2));
    amax = fmaxf(amax, __shfl_xor(amax, 4));

    int ebits = (int)((__float_as_uint(amax) >> 23) & 0xff);
    int sb;
    float inv;
    if (amax > 0.0f) {
        sb = ebits - 2; if (sb < 0) sb = 0;
        inv = __uint_as_float((unsigned)((256 - ebits) & 255) << 23);
    } else {
        sb = 127;              // scale 1.0, all-zero block
        inv = 0.0f;
    }

    int c0 = enc1(f.x, inv), c1 = enc1(f.y, inv);
    int c2 = enc1(f.z, inv), c3 = enc1(f.w, inv);
    ((unsigned short*)dq)[idx] =
        (unsigned short)(c0 | (c1 << 4) | (c2 << 8) | (c3 << 12));
    if ((idx & 7) == 0) {
        long m  = idx >> s4;                       // row
        int  kb = (int)((idx & ((1L << s4) - 1)) >> 3);  // k-block
        ds[(size_t)kb * rows + m] = (uint8_t)sb;   // transposed: [kb][row]
    }
}

// ---------- fp4 GEMM: C[M,N] = (Aq,AscT) x (Wq,WscT)^T + bias ----------
// 256 threads = 4 waves 2(M) x 2(N); per-wave output 64x64 = acc[2][2] of
// 32x32 blocks (16 f32 each).
// 32x32x64 frag: A row = lane&31, k-block (32 elems, 16B) = lane>>5;
//                B col = lane&31 (= W row), same k-split.
// Scale operand: e8m0 byte of the lane's own (row, k-block), opsel 0.
// C/D: col = lane&31 (n), row = (reg&3) + 8*(reg>>2) + 4*(lane>>5) (m).
//
// LDS rows are 64B = 4 x 16B chunks; slot c stores global chunk
// c ^ ((row>>1)&3) (applied on DMA source AND on read) so the wave's
// b128 frag reads spread 8 lanes x 16B per 4-bank group (conflict-free).

__global__ __launch_bounds__(256, 4) void gemm_fp4_v6(
        const uint8_t* __restrict__ Aq, const uint8_t* __restrict__ AscT,
        const uint8_t* __restrict__ Wq, const uint8_t* __restrict__ WscT,
        const float* __restrict__ bias, float* __restrict__ C,
        int M, int N, int K) {
    __shared__ __align__(16) uint8_t sA[2][BM * 64];   // 2 x 8 KB
    __shared__ __align__(16) uint8_t sB[2][BN * 64];   // 2 x 8 KB

    const int tid = threadIdx.x;
    const int lane = tid & 63;
    const int w = tid >> 6;
    const int wr = w >> 1;           // 0..1 (M)
    const int wc = w & 1;            // 0..1 (N)
    const int row32 = lane & 31;
    const int q2 = lane >> 5;        // k-block half within a 64-K step

    // XCD-aware bijective remap (grid 1024, id%8 = XCD)
    const int id = blockIdx.x;
    const int g = id & 7, h = id >> 3;
    const int by = g + 8 * (h & 7);  // 0..63
    const int bx = h >> 3;           // 0..15
    const int m0 = by * BM;
    const int n0 = bx * BN;
    const int KB2 = K >> 1;
    const int NT = K / BK;           // 16

    const int rA = wr * 64 + row32;  // A row within tile
    const int rB = wc * 64 + row32;  // B row within tile
    const int swz = (row32 >> 1) & 3;
    // chunk offset for k-step ks: global chunk g = ks*2 + q2, slot = g ^ swz
    const int off0 = ((0 * 2 + q2) ^ swz) * 16;
    const int off1 = ((1 * 2 + q2) ^ swz) * 16;

    // scale pointers: lane's k-block row, advanced 4 blocks (=BK) per tile
    const uint8_t* pScA = AscT + (size_t)q2 * M + m0 + wr * 64 + row32;
    const uint8_t* pScB = WscT + (size_t)q2 * N + n0 + wc * 64 + row32;

    floatx16 acc[2][2];
#pragma unroll
    for (int i = 0; i < 2; i++)
#pragma unroll
        for (int j = 0; j < 2; j++)
#pragma unroll
            for (int r = 0; r < 16; r++) acc[i][j][r] = 0.f;

    // 4 uniform DMA insts per thread per tile: 2 A + 2 B (16B each)
    auto stage = [&](int tt) {
        const int bb = tt & 1;
        const int kb = tt * 64;                 // byte offset along packed K
#pragma unroll
        for (int it = 0; it < 2; ++it) {
            int idx = it * 256 + tid;           // 0..511 16B chunks
            int row = idx >> 2, c = idx & 3;
            int gc = c ^ ((row >> 1) & 3);      // pre-swizzled source chunk
            const uint8_t* src = Aq + (size_t)(m0 + row) * KB2 + kb + gc * 16;
            __builtin_amdgcn_global_load_lds((GLOBAL_AS void*)src,
                (LDS_AS void*)(&sA[bb][idx * 16]), 16, 0, 0);
        }
#pragma unroll
        for (int it = 0; it < 2; ++it) {
            int idx = it * 256 + tid;
            int row = idx >> 2, c = idx & 3;
            int gc = c ^ ((row >> 1) & 3);
            const uint8_t* src = Wq + (size_t)(n0 + row) * KB2 + kb + gc * 16;
            __builtin_amdgcn_global_load_lds((GLOBAL_AS void*)src,
                (LDS_AS void*)(&sB[bb][idx * 16]), 16, 0, 0);
        }
    };

    // ---- prologue: stage tiles 0,1; ensure tile 0 landed, keep 1 flying ----
    stage(0);
    stage(1);
    asm volatile("s_waitcnt vmcnt(4)" ::: "memory");
    __builtin_amdgcn_sched_barrier(0);
    __builtin_amdgcn_s_barrier();

    for (int t = 0; t < NT; ++t) {
        const int p = t & 1;
        const uint8_t* pa = sA[p];
        const uint8_t* pb = sB[p];

        // scales for tile t: 8 coalesced ubyte loads (vm counter)
        int sa[2][2], sb[2][2];
#pragma unroll
        for (int ks = 0; ks < 2; ++ks)
#pragma unroll
            for (int i = 0; i < 2; ++i) {
                sa[ks][i] = (int)pScA[(size_t)(2 * ks) * M + i * 32];
                sb[ks][i] = (int)pScB[(size_t)(2 * ks) * N + i * 32];
            }

        // fragment reads: 8 x ds_read_b128 (lgkm counter)
        int4 fa[2][2], fb[2][2];
#pragma unroll
        for (int i = 0; i < 2; ++i) {
            fa[0][i] = *(const int4*)(pa + (rA + i * 32) * 64 + off0);
            fa[1][i] = *(const int4*)(pa + (rA + i * 32) * 64 + off1);
            fb[0][i] = *(const int4*)(pb + (rB + i * 32) * 64 + off0);
            fb[1][i] = *(const int4*)(pb + (rB + i * 32) * 64 + off1);
        }

        asm volatile("s_waitcnt lgkmcnt(0)" ::: "memory");
        __builtin_amdgcn_sched_barrier(0);
        __builtin_amdgcn_s_barrier();       // all waves done reading buf p

        if (t + 2 < NT) stage(t + 2);       // overwrite buf p (just freed)

        // wait: my scales S_t + my share of D_{t+1} landed; D_{t+2} flies
        if (t + 2 < NT) asm volatile("s_waitcnt vmcnt(4)" ::: "memory");
        else            asm volatile("s_waitcnt vmcnt(0)" ::: "memory");
        __builtin_amdgcn_sched_barrier(0);

        __builtin_amdgcn_s_setprio(1);
#pragma unroll
        for (int ks = 0; ks < 2; ++ks) {
            intx8 a0, a1, b0, b1;
            a0[0] = fa[ks][0].x; a0[1] = fa[ks][0].y; a0[2] = fa[ks][0].z; a0[3] = fa[ks][0].w;
            a1[0] = fa[ks][1].x; a1[1] = fa[ks][1].y; a1[2] = fa[ks][1].z; a1[3] = fa[ks][1].w;
            b0[0] = fb[ks][0].x; b0[1] = fb[ks][0].y; b0[2] = fb[ks][0].z; b0[3] = fb[ks][0].w;
            b1[0] = fb[ks][1].x; b1[1] = fb[ks][1].y; b1[2] = fb[ks][1].z; b1[3] = fb[ks][1].w;
#pragma unroll
            for (int z = 4; z < 8; ++z) { a0[z] = 0; a1[z] = 0; b0[z] = 0; b1[z] = 0; }
            acc[0][0] = __builtin_amdgcn_mfma_scale_f32_32x32x64_f8f6f4(
                a0, b0, acc[0][0], 4, 4, 0, sa[ks][0], 0, sb[ks][0]);
            acc[0][1] = __builtin_amdgcn_mfma_scale_f32_32x32x64_f8f6f4(
                a0, b1, acc[0][1], 4, 4, 0, sa[ks][0], 0, sb[ks][1]);
            acc[1][0] = __builtin_amdgcn_mfma_scale_f32_32x32x64_f8f6f4(
                a1, b0, acc[1][0], 4, 4, 0, sa[ks][1], 0, sb[ks][0]);
            acc[1][1] = __builtin_amdgcn_mfma_scale_f32_32x32x64_f8f6f4(
                a1, b1, acc[1][1], 4, 4, 0, sa[ks][1], 0, sb[ks][1]);
        }
        __builtin_amdgcn_s_setprio(0);
        __builtin_amdgcn_s_barrier();       // D_{t+1} visible to all

        pScA += (size_t)4 * M;              // advance 4 k-blocks
        pScB += (size_t)4 * N;
    }

    // ---- epilogue: col = lane&31 (n), row = (r&3)+8*(r>>2)+4*q2 (m) ----
#pragma unroll
    for (int j = 0; j < 2; ++j) {
        int n = n0 + wc * 64 + j * 32 + row32;
        float bv = bias[n];
#pragma unroll
        for (int i = 0; i < 2; ++i) {
            int mb = m0 + wr * 64 + i * 32 + 4 * q2;
#pragma unroll
            for (int r = 0; r < 16; ++r) {
                int m = mb + (r & 3) + 8 * (r >> 2);
                C[(size_t)m * N + n] = acc[i][j][r] + bv;
            }
        }
    }
}

// ---------------- launch ----------------

extern "C" void kernel_launch(void* const* d_in, const int* in_sizes, int n_in,
                              void* d_out, int out_size, void* d_ws, size_t ws_size,
                              hipStream_t stream) {
    const float* inp  = (const float*)d_in[0];
    const float* wgt  = (const float*)d_in[1];
    const float* bias = (const float*)d_in[2];
    float* out = (float*)d_out;

    const int N = in_sizes[2];                 // 2048
    const int K = in_sizes[1] / N;             // 2048
    const long M = (long)in_sizes[0] / K;      // 8192

    uint8_t* Aq4  = (uint8_t*)d_ws;            // M*K/2
    uint8_t* Wq4  = Aq4 + (size_t)M * K / 2;   // N*K/2
    uint8_t* AscT = Wq4 + (size_t)N * K / 2;   // M*K/32 (layout [K/32][M])
    uint8_t* WscT = AscT + (size_t)M * K / 32; // N*K/32 (layout [K/32][N])

    int s4 = 0;
    while ((1 << s4) < (K >> 2)) ++s4;         // log2(K/4) = 9

    long na4   = (long)M * K / 4;
    long ntot4 = na4 + (long)N * K / 4;
    quant_mxfp4_v4<<<dim3((ntot4 + 255) / 256), dim3(256), 0, stream>>>(
        inp, Aq4, AscT, wgt, Wq4, WscT, na4, ntot4, s4, M, (long)N);

    dim3 grid((N / BN) * (int)(M / BM));       // 16*64 = 1024 = 4/CU
    gemm_fp4_v6<<<grid, dim3(256), 0, stream>>>(
        Aq4, AscT, Wq4, WscT, bias, out, (int)M, N, K);
}